// Round 1
// baseline (891.181 us; speedup 1.0000x reference)
//
#include <hip/hip_runtime.h>
#include <math.h>

#define NN 50000
#define NE 800000
#define IN_CH 256
#define HEADS 4
#define OUT_CH 32
#define HC 128            // HEADS*OUT_CH
#define NEG_SLOPE 0.2f
#define GAT_EPS 1e-16f

// workspace layout, in floats
#define OFF_H      0
#define OFF_AI     (NN*HC)                  // 6,400,000
#define OFF_AJ     (OFF_AI + NN*HEADS)
#define OFF_S      (OFF_AJ + NN*HEADS)
#define OFF_MKEY   (OFF_S + NN*HEADS)       // stored as unsigned
#define OFF_EDGE   (OFF_MKEY + NN*HEADS)    // NE*HEADS floats

__device__ __forceinline__ unsigned fkey(float f) {
    unsigned b = __float_as_uint(f);
    return (b & 0x80000000u) ? ~b : (b | 0x80000000u);
}
__device__ __forceinline__ float funkey(unsigned u) {
    unsigned b = (u & 0x80000000u) ? (u & 0x7FFFFFFFu) : ~u;
    return __uint_as_float(b);
}

// init: out = bias (broadcast), s = 0, mkey = 0 (key-space -inf)
__global__ void k_init(float* __restrict__ out, const float* __restrict__ bias,
                       float* __restrict__ s, unsigned* __restrict__ mkey) {
    int idx = blockIdx.x * blockDim.x + threadIdx.x;
    const int out4 = NN * HC / 4;            // 1,600,000 float4 stores
    if (idx < out4) {
        float4 b = ((const float4*)bias)[idx & 31];   // HC/4 = 32
        ((float4*)out)[idx] = b;
    } else {
        int extra = idx - out4;
        if (extra < NN * HEADS) { s[extra] = 0.0f; mkey[extra] = 0u; }
    }
}

// fp32 tiled GEMM: H[n,c] = sum_k A[n,k] * W[k,c];  M=50000, K=256, N=128
#define BM 64
#define BK 32
__global__ __launch_bounds__(256) void k_gemm(const float* __restrict__ A,
                                              const float* __restrict__ W,
                                              float* __restrict__ H) {
    __shared__ float sA[BM][BK + 4];   // pad to stride 36 to break bank aliasing
    __shared__ float sW[BK][HC];
    const int tid = threadIdx.x;
    const int row0 = blockIdx.x * BM;
    const int c0 = (tid & 15) * 8;     // 16 col-groups of 8
    const int r0 = (tid >> 4) * 4;     // 16 row-groups of 4

    float acc[4][8];
#pragma unroll
    for (int i = 0; i < 4; i++)
#pragma unroll
        for (int j = 0; j < 8; j++) acc[i][j] = 0.0f;

    for (int k0 = 0; k0 < IN_CH; k0 += BK) {
        // A tile: 64x32 floats = 512 float4; 2 per thread
#pragma unroll
        for (int l = 0; l < 2; l++) {
            int f4 = tid + l * 256;
            int r = f4 >> 3;
            int kk = (f4 & 7) * 4;
            int grow = row0 + r;
            float4 v = make_float4(0.f, 0.f, 0.f, 0.f);
            if (grow < NN) v = *(const float4*)&A[(size_t)grow * IN_CH + k0 + kk];
            *(float4*)&sA[r][kk] = v;
        }
        // W tile: 32x128 floats = 1024 float4; 4 per thread
#pragma unroll
        for (int l = 0; l < 4; l++) {
            int f4 = tid + l * 256;
            int r = f4 >> 5;
            int cc = (f4 & 31) * 4;
            *(float4*)&sW[r][cc] = *(const float4*)&W[(size_t)(k0 + r) * HC + cc];
        }
        __syncthreads();
#pragma unroll
        for (int k = 0; k < BK; k++) {
            float av[4];
#pragma unroll
            for (int i = 0; i < 4; i++) av[i] = sA[r0 + i][k];
            float wv[8];
            *(float4*)&wv[0] = *(float4*)&sW[k][c0];
            *(float4*)&wv[4] = *(float4*)&sW[k][c0 + 4];
#pragma unroll
            for (int i = 0; i < 4; i++)
#pragma unroll
                for (int j = 0; j < 8; j++)
                    acc[i][j] = fmaf(av[i], wv[j], acc[i][j]);
        }
        __syncthreads();
    }
#pragma unroll
    for (int i = 0; i < 4; i++) {
        int grow = row0 + r0 + i;
        if (grow < NN) {
            float4 o0 = make_float4(acc[i][0], acc[i][1], acc[i][2], acc[i][3]);
            float4 o1 = make_float4(acc[i][4], acc[i][5], acc[i][6], acc[i][7]);
            *(float4*)&H[(size_t)grow * HC + c0] = o0;
            *(float4*)&H[(size_t)grow * HC + c0 + 4] = o1;
        }
    }
}

// per-(node,head) attention dots: ai = h . att_i, aj = h . att_j
__global__ void k_att(const float* __restrict__ Hm, const float* __restrict__ att,
                      float* __restrict__ ai, float* __restrict__ aj) {
    int idx = blockIdx.x * blockDim.x + threadIdx.x;
    if (idx >= NN * HEADS) return;
    int n = idx >> 2, hh = idx & 3;
    const float* hp  = Hm + (size_t)n * HC + hh * OUT_CH;
    const float* ati = att + hh * 2 * OUT_CH;
    const float* atj = ati + OUT_CH;
    float si = 0.f, sj = 0.f;
#pragma unroll
    for (int c = 0; c < OUT_CH; c++) {
        float hv = hp[c];
        si = fmaf(hv, ati[c], si);
        sj = fmaf(hv, atj[c], sj);
    }
    ai[idx] = si;
    aj[idx] = sj;
}

// per-(edge,head): alpha = lrelu(ai[dst] + aj[src]); segment-max via atomicMax on key
__global__ void k_alpha(const int* __restrict__ adj, const float* __restrict__ ai,
                        const float* __restrict__ aj, float* __restrict__ ealpha,
                        unsigned* __restrict__ mkey) {
    int idx = blockIdx.x * blockDim.x + threadIdx.x;
    if (idx >= NE * HEADS) return;
    int e = idx >> 2, hh = idx & 3;
    int dst = adj[e];
    int src = adj[NE + e];
    float al = ai[dst * HEADS + hh] + aj[src * HEADS + hh];
    al = (al > 0.f) ? al : NEG_SLOPE * al;
    ealpha[idx] = al;
    atomicMax(&mkey[dst * HEADS + hh], fkey(al));
}

// per-(edge,head): e = exp(alpha - m[dst]); segment-sum via atomicAdd
__global__ void k_exp(const int* __restrict__ adj, const unsigned* __restrict__ mkey,
                      float* __restrict__ ealpha, float* __restrict__ s) {
    int idx = blockIdx.x * blockDim.x + threadIdx.x;
    if (idx >= NE * HEADS) return;
    int e = idx >> 2, hh = idx & 3;
    int dst = adj[e];
    float m = funkey(mkey[dst * HEADS + hh]);
    float ex = __expf(ealpha[idx] - m);
    ealpha[idx] = ex;
    atomicAdd(&s[dst * HEADS + hh], ex);
}

// one wave per edge; lane handles 2 channels; out[dst] += h[src] * a
__global__ __launch_bounds__(256) void k_agg(const int* __restrict__ adj,
                                             const float* __restrict__ Hm,
                                             const float* __restrict__ ealpha,
                                             const float* __restrict__ s,
                                             float* __restrict__ out) {
    int gid = blockIdx.x * blockDim.x + threadIdx.x;
    int e = gid >> 6;
    int lane = gid & 63;
    if (e >= NE) return;
    int dst = adj[e];
    int src = adj[NE + e];
    int c0 = lane * 2;
    int hh = c0 >> 5;
    float aval = ealpha[e * HEADS + hh] / (s[dst * HEADS + hh] + GAT_EPS);
    float2 hv = *(const float2*)&Hm[(size_t)src * HC + c0];
    atomicAdd(&out[(size_t)dst * HC + c0],     hv.x * aval);
    atomicAdd(&out[(size_t)dst * HC + c0 + 1], hv.y * aval);
}

extern "C" void kernel_launch(void* const* d_in, const int* in_sizes, int n_in,
                              void* d_out, int out_size, void* d_ws, size_t ws_size,
                              hipStream_t stream) {
    const float* nodes  = (const float*)d_in[0];
    const int*   adj    = (const int*)d_in[1];     // int64 in ref -> int32 here
    const float* weight = (const float*)d_in[2];
    const float* att    = (const float*)d_in[3];
    const float* bias   = (const float*)d_in[4];
    float* out = (float*)d_out;
    float* ws  = (float*)d_ws;

    float*    Hm     = ws + OFF_H;
    float*    ai     = ws + OFF_AI;
    float*    aj     = ws + OFF_AJ;
    float*    s      = ws + OFF_S;
    unsigned* mkey   = (unsigned*)(ws + OFF_MKEY);
    float*    ealpha = ws + OFF_EDGE;

    {
        int total = NN * HC / 4 + NN * HEADS;
        k_init<<<(total + 255) / 256, 256, 0, stream>>>(out, bias, s, mkey);
    }
    k_gemm<<<(NN + BM - 1) / BM, 256, 0, stream>>>(nodes, weight, Hm);
    k_att<<<(NN * HEADS + 255) / 256, 256, 0, stream>>>(Hm, att, ai, aj);
    k_alpha<<<(NE * HEADS + 255) / 256, 256, 0, stream>>>(adj, ai, aj, ealpha, mkey);
    k_exp<<<(NE * HEADS + 255) / 256, 256, 0, stream>>>(adj, mkey, ealpha, s);
    k_agg<<<(NE * 64) / 256, 256, 0, stream>>>(adj, Hm, ealpha, s, out);
}

// Round 6
// 415.537 us; speedup vs baseline: 2.1446x; 2.1446x over previous
//
#include <hip/hip_runtime.h>
#include <math.h>

#define NN 50000
#define NE 800000
#define IN_CH 256
#define HEADS 4
#define OUT_CH 32
#define HC 128            // HEADS*OUT_CH
#define NEG_SLOPE 0.2f
#define GAT_EPS 1e-16f

// workspace layout, in 4-byte units
#define OFF_H      0                        // NN*HC floats
#define OFF_AI     (NN*HC)                  // NN*HEADS floats
#define OFF_AJ     (OFF_AI + NN*HEADS)      // NN*HEADS floats
#define OFF_ROW    (OFF_AJ + NN*HEADS)      // NN+1 ints
#define OFF_CUR    (OFF_ROW + NN + 4)       // NN ints
#define OFF_HIST   (OFF_CUR + NN + 4)       // NN ints
#define OFF_ESRC   (OFF_HIST + NN + 4)      // NE ints

__global__ void k_zero(int* __restrict__ hist) {
    int i = blockIdx.x * blockDim.x + threadIdx.x;
    if (i < NN) hist[i] = 0;
}

// fp32 tiled GEMM: H[n,c] = sum_k A[n,k] * W[k,c];  M=50000, K=256, N=128
#define BM 64
#define BK 32
__global__ __launch_bounds__(256) void k_gemm(const float* __restrict__ A,
                                              const float* __restrict__ W,
                                              float* __restrict__ H) {
    __shared__ float sA[BM][BK + 4];
    __shared__ float sW[BK][HC];
    const int tid = threadIdx.x;
    const int row0 = blockIdx.x * BM;
    const int c0 = (tid & 15) * 8;
    const int r0 = (tid >> 4) * 4;

    float acc[4][8];
#pragma unroll
    for (int i = 0; i < 4; i++)
#pragma unroll
        for (int j = 0; j < 8; j++) acc[i][j] = 0.0f;

    for (int k0 = 0; k0 < IN_CH; k0 += BK) {
#pragma unroll
        for (int l = 0; l < 2; l++) {
            int f4 = tid + l * 256;
            int r = f4 >> 3;
            int kk = (f4 & 7) * 4;
            int grow = row0 + r;
            float4 v = make_float4(0.f, 0.f, 0.f, 0.f);
            if (grow < NN) v = *(const float4*)&A[(size_t)grow * IN_CH + k0 + kk];
            *(float4*)&sA[r][kk] = v;
        }
#pragma unroll
        for (int l = 0; l < 4; l++) {
            int f4 = tid + l * 256;
            int r = f4 >> 5;
            int cc = (f4 & 31) * 4;
            *(float4*)&sW[r][cc] = *(const float4*)&W[(size_t)(k0 + r) * HC + cc];
        }
        __syncthreads();
#pragma unroll
        for (int k = 0; k < BK; k++) {
            float av[4];
#pragma unroll
            for (int i = 0; i < 4; i++) av[i] = sA[r0 + i][k];
            float wv[8];
            *(float4*)&wv[0] = *(float4*)&sW[k][c0];
            *(float4*)&wv[4] = *(float4*)&sW[k][c0 + 4];
#pragma unroll
            for (int i = 0; i < 4; i++)
#pragma unroll
                for (int j = 0; j < 8; j++)
                    acc[i][j] = fmaf(av[i], wv[j], acc[i][j]);
        }
        __syncthreads();
    }
#pragma unroll
    for (int i = 0; i < 4; i++) {
        int grow = row0 + r0 + i;
        if (grow < NN) {
            float4 o0 = make_float4(acc[i][0], acc[i][1], acc[i][2], acc[i][3]);
            float4 o1 = make_float4(acc[i][4], acc[i][5], acc[i][6], acc[i][7]);
            *(float4*)&H[(size_t)grow * HC + c0] = o0;
            *(float4*)&H[(size_t)grow * HC + c0 + 4] = o1;
        }
    }
}

// per-(node,head) attention dots: ai = h . att_i, aj = h . att_j
__global__ void k_att(const float* __restrict__ Hm, const float* __restrict__ att,
                      float* __restrict__ ai, float* __restrict__ aj) {
    int idx = blockIdx.x * blockDim.x + threadIdx.x;
    if (idx >= NN * HEADS) return;
    int n = idx >> 2, hh = idx & 3;
    const float* hp  = Hm + (size_t)n * HC + hh * OUT_CH;
    const float* ati = att + hh * 2 * OUT_CH;
    const float* atj = ati + OUT_CH;
    float si = 0.f, sj = 0.f;
#pragma unroll
    for (int c = 0; c < OUT_CH; c++) {
        float hv = hp[c];
        si = fmaf(hv, ati[c], si);
        sj = fmaf(hv, atj[c], sj);
    }
    ai[idx] = si;
    aj[idx] = sj;
}

__global__ void k_hist(const int* __restrict__ adj, int* __restrict__ hist) {
    int e = blockIdx.x * blockDim.x + threadIdx.x;
    if (e < NE) atomicAdd(&hist[adj[e]], 1);
}

// single-block exclusive scan of hist[NN] -> row[NN+1], cursor[NN]
#define SCAN_T 1024
#define CHUNK 49          // 1024*49 = 50176 >= 50000
__global__ __launch_bounds__(SCAN_T) void k_scan(const int* __restrict__ hist,
                                                 int* __restrict__ row,
                                                 int* __restrict__ cur) {
    __shared__ int part[SCAN_T];
    int t = threadIdx.x;
    int base = t * CHUNK;
    int end = min(base + CHUNK, NN);
    int local = 0;
    for (int i = base; i < end; i++) local += hist[i];
    part[t] = local;
    __syncthreads();
    // inclusive Hillis-Steele scan over 1024 partials
    for (int off = 1; off < SCAN_T; off <<= 1) {
        int v = (t >= off) ? part[t - off] : 0;
        __syncthreads();
        part[t] += v;
        __syncthreads();
    }
    int run = (t == 0) ? 0 : part[t - 1];
    for (int i = base; i < end; i++) {
        int c = hist[i];
        row[i] = run;
        cur[i] = run;
        run += c;
    }
    if (t == SCAN_T - 1) row[NN] = part[SCAN_T - 1];   // == NE
}

__global__ void k_scatter(const int* __restrict__ adj, int* __restrict__ cur,
                          int* __restrict__ esrc) {
    int e = blockIdx.x * blockDim.x + threadIdx.x;
    if (e >= NE) return;
    int dst = adj[e];
    int src = adj[NE + e];
    int pos = atomicAdd(&cur[dst], 1);
    esrc[pos] = src;
}

__device__ __forceinline__ float lrelu(float x) {
    return x > 0.f ? x : NEG_SLOPE * x;
}

// one wave per node: segment-max, exp-sum, weighted gather — all in registers
__global__ __launch_bounds__(256) void k_gather(const int* __restrict__ row,
                                                const int* __restrict__ esrc,
                                                const float* __restrict__ ai,
                                                const float* __restrict__ aj,
                                                const float* __restrict__ Hm,
                                                const float* __restrict__ bias,
                                                float* __restrict__ out) {
    int gid = blockIdx.x * blockDim.x + threadIdx.x;
    int nid = gid >> 6;
    int lane = gid & 63;
    if (nid >= NN) return;
    int r0 = row[nid];
    int deg = row[nid + 1] - r0;

    float4 aiv = *(const float4*)&ai[nid * 4];

    // pass 1: per-head max over incoming edges
    float mx0 = -INFINITY, mx1 = -INFINITY, mx2 = -INFINITY, mx3 = -INFINITY;
    for (int k = lane; k < deg; k += 64) {
        int s = esrc[r0 + k];
        float4 ajv = *(const float4*)&aj[s * 4];
        mx0 = fmaxf(mx0, lrelu(aiv.x + ajv.x));
        mx1 = fmaxf(mx1, lrelu(aiv.y + ajv.y));
        mx2 = fmaxf(mx2, lrelu(aiv.z + ajv.z));
        mx3 = fmaxf(mx3, lrelu(aiv.w + ajv.w));
    }
#pragma unroll
    for (int off = 32; off; off >>= 1) {
        mx0 = fmaxf(mx0, __shfl_xor(mx0, off));
        mx1 = fmaxf(mx1, __shfl_xor(mx1, off));
        mx2 = fmaxf(mx2, __shfl_xor(mx2, off));
        mx3 = fmaxf(mx3, __shfl_xor(mx3, off));
    }

    // pass 2: per-head exp-sum
    float s0 = 0.f, s1 = 0.f, s2 = 0.f, s3 = 0.f;
    for (int k = lane; k < deg; k += 64) {
        int s = esrc[r0 + k];
        float4 ajv = *(const float4*)&aj[s * 4];
        s0 += __expf(lrelu(aiv.x + ajv.x) - mx0);
        s1 += __expf(lrelu(aiv.y + ajv.y) - mx1);
        s2 += __expf(lrelu(aiv.z + ajv.z) - mx2);
        s3 += __expf(lrelu(aiv.w + ajv.w) - mx3);
    }
#pragma unroll
    for (int off = 32; off; off >>= 1) {
        s0 += __shfl_xor(s0, off);
        s1 += __shfl_xor(s1, off);
        s2 += __shfl_xor(s2, off);
        s3 += __shfl_xor(s3, off);
    }

    // pass 3: weighted aggregation; lane owns channels c0, c0+1 (head hh)
    int c0 = lane * 2;
    int hh = lane >> 4;                 // (lane*2)>>5
    float mh  = (hh & 2) ? ((hh & 1) ? mx3 : mx2) : ((hh & 1) ? mx1 : mx0);
    float sh  = (hh & 2) ? ((hh & 1) ? s3 : s2) : ((hh & 1) ? s1 : s0);
    float aih = (hh & 2) ? ((hh & 1) ? aiv.w : aiv.z) : ((hh & 1) ? aiv.y : aiv.x);
    float inv = 1.0f / (sh + GAT_EPS);

    float accx = 0.f, accy = 0.f;
#pragma unroll 4
    for (int k = 0; k < deg; k++) {
        int s = esrc[r0 + k];           // same addr across wave -> broadcast
        float al = lrelu(aih + aj[s * 4 + hh]);
        float a = __expf(al - mh) * inv;
        float2 hv = *(const float2*)&Hm[(size_t)s * HC + c0];
        accx = fmaf(hv.x, a, accx);
        accy = fmaf(hv.y, a, accy);
    }
    out[(size_t)nid * HC + c0]     = accx + bias[c0];
    out[(size_t)nid * HC + c0 + 1] = accy + bias[c0 + 1];
}

extern "C" void kernel_launch(void* const* d_in, const int* in_sizes, int n_in,
                              void* d_out, int out_size, void* d_ws, size_t ws_size,
                              hipStream_t stream) {
    const float* nodes  = (const float*)d_in[0];
    const int*   adj    = (const int*)d_in[1];
    const float* weight = (const float*)d_in[2];
    const float* att    = (const float*)d_in[3];
    const float* bias   = (const float*)d_in[4];
    float* out = (float*)d_out;
    float* ws  = (float*)d_ws;

    float* Hm   = ws + OFF_H;
    float* ai   = ws + OFF_AI;
    float* aj   = ws + OFF_AJ;
    int*   rowp = (int*)(ws + OFF_ROW);
    int*   cur  = (int*)(ws + OFF_CUR);
    int*   hist = (int*)(ws + OFF_HIST);
    int*   esrc = (int*)(ws + OFF_ESRC);

    k_zero<<<(NN + 255) / 256, 256, 0, stream>>>(hist);
    k_hist<<<(NE + 255) / 256, 256, 0, stream>>>(adj, hist);
    k_scan<<<1, SCAN_T, 0, stream>>>(hist, rowp, cur);
    k_scatter<<<(NE + 255) / 256, 256, 0, stream>>>(adj, cur, esrc);
    k_gemm<<<(NN + BM - 1) / BM, 256, 0, stream>>>(nodes, weight, Hm);
    k_att<<<(NN * HEADS + 255) / 256, 256, 0, stream>>>(Hm, att, ai, aj);
    k_gather<<<(NN * 64 + 255) / 256, 256, 0, stream>>>(rowp, esrc, ai, aj, Hm, bias, out);
}

// Round 8
// 316.418 us; speedup vs baseline: 2.8165x; 1.3133x over previous
//
#include <hip/hip_runtime.h>
#include <math.h>

#define NN 50000
#define NE 800000
#define IN_CH 256
#define HEADS 4
#define OUT_CH 32
#define HC 128            // HEADS*OUT_CH
#define NEG_SLOPE 0.2f
#define GAT_EPS 1e-16f

// parallel scan geometry: 49 blocks x 1024 elements (thread handles 4)
#define SBS 1024
#define NB  ((NN + SBS - 1) / SBS)   // 49

// workspace layout, in 4-byte units
#define OFF_H      0                        // NN*HC floats
#define OFF_AI     (NN*HC)                  // NN*HEADS floats
#define OFF_AJ     (OFF_AI + NN*HEADS)      // NN*HEADS floats
#define OFF_ROW    (OFF_AJ + NN*HEADS)      // NN+1 ints
#define OFF_CUR    (OFF_ROW + NN + 4)       // NN ints
#define OFF_HIST   (OFF_CUR + NN + 4)       // NN ints
#define OFF_BSUM   (OFF_HIST + NN + 4)      // NB ints (block sums)
#define OFF_BOFF   (OFF_BSUM + NB + 4)      // NB ints (block offsets)
#define OFF_ESRC   (OFF_BOFF + NB + 4)      // NE ints

__global__ void k_zero(int* __restrict__ hist) {
    int i = blockIdx.x * blockDim.x + threadIdx.x;
    if (i < NN) hist[i] = 0;
}

// fp32 tiled GEMM: H[n,c] = sum_k A[n,k] * W[k,c];  M=50000, K=256, N=128
#define BM 64
#define BK 32
__global__ __launch_bounds__(256) void k_gemm(const float* __restrict__ A,
                                              const float* __restrict__ W,
                                              float* __restrict__ H) {
    __shared__ float sA[BM][BK + 4];
    __shared__ float sW[BK][HC];
    const int tid = threadIdx.x;
    const int row0 = blockIdx.x * BM;
    const int c0 = (tid & 15) * 8;
    const int r0 = (tid >> 4) * 4;

    float acc[4][8];
#pragma unroll
    for (int i = 0; i < 4; i++)
#pragma unroll
        for (int j = 0; j < 8; j++) acc[i][j] = 0.0f;

    for (int k0 = 0; k0 < IN_CH; k0 += BK) {
#pragma unroll
        for (int l = 0; l < 2; l++) {
            int f4 = tid + l * 256;
            int r = f4 >> 3;
            int kk = (f4 & 7) * 4;
            int grow = row0 + r;
            float4 v = make_float4(0.f, 0.f, 0.f, 0.f);
            if (grow < NN) v = *(const float4*)&A[(size_t)grow * IN_CH + k0 + kk];
            *(float4*)&sA[r][kk] = v;
        }
#pragma unroll
        for (int l = 0; l < 4; l++) {
            int f4 = tid + l * 256;
            int r = f4 >> 5;
            int cc = (f4 & 31) * 4;
            *(float4*)&sW[r][cc] = *(const float4*)&W[(size_t)(k0 + r) * HC + cc];
        }
        __syncthreads();
#pragma unroll
        for (int k = 0; k < BK; k++) {
            float av[4];
#pragma unroll
            for (int i = 0; i < 4; i++) av[i] = sA[r0 + i][k];
            float wv[8];
            *(float4*)&wv[0] = *(float4*)&sW[k][c0];
            *(float4*)&wv[4] = *(float4*)&sW[k][c0 + 4];
#pragma unroll
            for (int i = 0; i < 4; i++)
#pragma unroll
                for (int j = 0; j < 8; j++)
                    acc[i][j] = fmaf(av[i], wv[j], acc[i][j]);
        }
        __syncthreads();
    }
#pragma unroll
    for (int i = 0; i < 4; i++) {
        int grow = row0 + r0 + i;
        if (grow < NN) {
            float4 o0 = make_float4(acc[i][0], acc[i][1], acc[i][2], acc[i][3]);
            float4 o1 = make_float4(acc[i][4], acc[i][5], acc[i][6], acc[i][7]);
            *(float4*)&H[(size_t)grow * HC + c0] = o0;
            *(float4*)&H[(size_t)grow * HC + c0 + 4] = o1;
        }
    }
}

// per-(node,head) attention dots: ai = h . att_i, aj = h . att_j
__global__ void k_att(const float* __restrict__ Hm, const float* __restrict__ att,
                      float* __restrict__ ai, float* __restrict__ aj) {
    int idx = blockIdx.x * blockDim.x + threadIdx.x;
    if (idx >= NN * HEADS) return;
    int n = idx >> 2, hh = idx & 3;
    const float* hp  = Hm + (size_t)n * HC + hh * OUT_CH;
    const float* ati = att + hh * 2 * OUT_CH;
    const float* atj = ati + OUT_CH;
    float si = 0.f, sj = 0.f;
#pragma unroll
    for (int c = 0; c < OUT_CH; c++) {
        float hv = hp[c];
        si = fmaf(hv, ati[c], si);
        sj = fmaf(hv, atj[c], sj);
    }
    ai[idx] = si;
    aj[idx] = sj;
}

__global__ void k_hist(const int* __restrict__ adj, int* __restrict__ hist) {
    int e = blockIdx.x * blockDim.x + threadIdx.x;
    if (e < NE) atomicAdd(&hist[adj[e]], 1);
}

// scan A: per-block (1024 elems) sum -> bsum[NB]
__global__ __launch_bounds__(256) void k_bsum(const int* __restrict__ hist,
                                              int* __restrict__ bsum) {
    int b = blockIdx.x, t = threadIdx.x;
    int i0 = b * SBS + t * 4;
    int s = 0;
#pragma unroll
    for (int j = 0; j < 4; j++) {
        int i = i0 + j;
        if (i < NN) s += hist[i];
    }
#pragma unroll
    for (int off = 32; off; off >>= 1) s += __shfl_xor(s, off);
    __shared__ int ws[4];
    int lane = t & 63, wid = t >> 6;
    if (lane == 0) ws[wid] = s;
    __syncthreads();
    if (t == 0) bsum[b] = ws[0] + ws[1] + ws[2] + ws[3];
}

// scan B: one wave exclusive-scans bsum[NB] -> boff[NB]  (NB=49 <= 64)
__global__ __launch_bounds__(64) void k_bscan(const int* __restrict__ bsum,
                                              int* __restrict__ boff) {
    int lane = threadIdx.x;
    int v = (lane < NB) ? bsum[lane] : 0;
    int inc = v;
#pragma unroll
    for (int off = 1; off < 64; off <<= 1) {
        int u = __shfl_up(inc, off);
        if (lane >= off) inc += u;
    }
    if (lane < NB) boff[lane] = inc - v;   // exclusive
}

// scan C: block-local exclusive scan + block offset -> row, cur; row[NN]=NE
__global__ __launch_bounds__(256) void k_bwrite(const int* __restrict__ hist,
                                                const int* __restrict__ boff,
                                                int* __restrict__ row,
                                                int* __restrict__ cur) {
    int b = blockIdx.x, t = threadIdx.x;
    int i0 = b * SBS + t * 4;
    int v[4];
    int s = 0;
#pragma unroll
    for (int j = 0; j < 4; j++) {
        int i = i0 + j;
        v[j] = (i < NN) ? hist[i] : 0;
        s += v[j];
    }
    int lane = t & 63, wid = t >> 6;
    int inc = s;
#pragma unroll
    for (int off = 1; off < 64; off <<= 1) {
        int u = __shfl_up(inc, off);
        if (lane >= off) inc += u;
    }
    __shared__ int wsum[4];
    if (lane == 63) wsum[wid] = inc;
    __syncthreads();
    int woff = 0;
    for (int w = 0; w < wid; w++) woff += wsum[w];
    int run = boff[b] + woff + (inc - s);   // thread-level exclusive prefix
#pragma unroll
    for (int j = 0; j < 4; j++) {
        int i = i0 + j;
        if (i < NN) {
            row[i] = run;
            cur[i] = run;
            run += v[j];
        }
    }
    if (b == 0 && t == 0) row[NN] = NE;     // total edge count is constant
}

__global__ void k_scatter(const int* __restrict__ adj, int* __restrict__ cur,
                          int* __restrict__ esrc) {
    int e = blockIdx.x * blockDim.x + threadIdx.x;
    if (e >= NE) return;
    int dst = adj[e];
    int src = adj[NE + e];
    int pos = atomicAdd(&cur[dst], 1);
    esrc[pos] = src;
}

__device__ __forceinline__ float lrelu(float x) {
    return x > 0.f ? x : NEG_SLOPE * x;
}

// one wave per node: segment-max, exp-sum, weighted gather — all in registers
__global__ __launch_bounds__(256) void k_gather(const int* __restrict__ row,
                                                const int* __restrict__ esrc,
                                                const float* __restrict__ ai,
                                                const float* __restrict__ aj,
                                                const float* __restrict__ Hm,
                                                const float* __restrict__ bias,
                                                float* __restrict__ out) {
    int gid = blockIdx.x * blockDim.x + threadIdx.x;
    int nid = gid >> 6;
    int lane = gid & 63;
    if (nid >= NN) return;
    int r0 = row[nid];
    int deg = row[nid + 1] - r0;

    float4 aiv = *(const float4*)&ai[nid * 4];

    // pass 1: per-head max over incoming edges
    float mx0 = -INFINITY, mx1 = -INFINITY, mx2 = -INFINITY, mx3 = -INFINITY;
    for (int k = lane; k < deg; k += 64) {
        int s = esrc[r0 + k];
        float4 ajv = *(const float4*)&aj[s * 4];
        mx0 = fmaxf(mx0, lrelu(aiv.x + ajv.x));
        mx1 = fmaxf(mx1, lrelu(aiv.y + ajv.y));
        mx2 = fmaxf(mx2, lrelu(aiv.z + ajv.z));
        mx3 = fmaxf(mx3, lrelu(aiv.w + ajv.w));
    }
#pragma unroll
    for (int off = 32; off; off >>= 1) {
        mx0 = fmaxf(mx0, __shfl_xor(mx0, off));
        mx1 = fmaxf(mx1, __shfl_xor(mx1, off));
        mx2 = fmaxf(mx2, __shfl_xor(mx2, off));
        mx3 = fmaxf(mx3, __shfl_xor(mx3, off));
    }

    // pass 2: per-head exp-sum
    float s0 = 0.f, s1 = 0.f, s2 = 0.f, s3 = 0.f;
    for (int k = lane; k < deg; k += 64) {
        int s = esrc[r0 + k];
        float4 ajv = *(const float4*)&aj[s * 4];
        s0 += __expf(lrelu(aiv.x + ajv.x) - mx0);
        s1 += __expf(lrelu(aiv.y + ajv.y) - mx1);
        s2 += __expf(lrelu(aiv.z + ajv.z) - mx2);
        s3 += __expf(lrelu(aiv.w + ajv.w) - mx3);
    }
#pragma unroll
    for (int off = 32; off; off >>= 1) {
        s0 += __shfl_xor(s0, off);
        s1 += __shfl_xor(s1, off);
        s2 += __shfl_xor(s2, off);
        s3 += __shfl_xor(s3, off);
    }

    // pass 3: weighted aggregation; lane owns channels c0, c0+1 (head hh)
    int c0 = lane * 2;
    int hh = lane >> 4;                 // (lane*2)>>5
    float mh  = (hh & 2) ? ((hh & 1) ? mx3 : mx2) : ((hh & 1) ? mx1 : mx0);
    float sh  = (hh & 2) ? ((hh & 1) ? s3 : s2) : ((hh & 1) ? s1 : s0);
    float aih = (hh & 2) ? ((hh & 1) ? aiv.w : aiv.z) : ((hh & 1) ? aiv.y : aiv.x);
    float inv = 1.0f / (sh + GAT_EPS);

    float accx = 0.f, accy = 0.f;
#pragma unroll 4
    for (int k = 0; k < deg; k++) {
        int s = esrc[r0 + k];           // same addr across wave -> broadcast
        float al = lrelu(aih + aj[s * 4 + hh]);
        float a = __expf(al - mh) * inv;
        float2 hv = *(const float2*)&Hm[(size_t)s * HC + c0];
        accx = fmaf(hv.x, a, accx);
        accy = fmaf(hv.y, a, accy);
    }
    out[(size_t)nid * HC + c0]     = accx + bias[c0];
    out[(size_t)nid * HC + c0 + 1] = accy + bias[c0 + 1];
}

extern "C" void kernel_launch(void* const* d_in, const int* in_sizes, int n_in,
                              void* d_out, int out_size, void* d_ws, size_t ws_size,
                              hipStream_t stream) {
    const float* nodes  = (const float*)d_in[0];
    const int*   adj    = (const int*)d_in[1];
    const float* weight = (const float*)d_in[2];
    const float* att    = (const float*)d_in[3];
    const float* bias   = (const float*)d_in[4];
    float* out = (float*)d_out;
    float* ws  = (float*)d_ws;

    float* Hm   = ws + OFF_H;
    float* ai   = ws + OFF_AI;
    float* aj   = ws + OFF_AJ;
    int*   rowp = (int*)(ws + OFF_ROW);
    int*   cur  = (int*)(ws + OFF_CUR);
    int*   hist = (int*)(ws + OFF_HIST);
    int*   bsum = (int*)(ws + OFF_BSUM);
    int*   boff = (int*)(ws + OFF_BOFF);
    int*   esrc = (int*)(ws + OFF_ESRC);

    k_zero<<<(NN + 255) / 256, 256, 0, stream>>>(hist);
    k_hist<<<(NE + 255) / 256, 256, 0, stream>>>(adj, hist);
    k_bsum<<<NB, 256, 0, stream>>>(hist, bsum);
    k_bscan<<<1, 64, 0, stream>>>(bsum, boff);
    k_bwrite<<<NB, 256, 0, stream>>>(hist, boff, rowp, cur);
    k_scatter<<<(NE + 255) / 256, 256, 0, stream>>>(adj, cur, esrc);
    k_gemm<<<(NN + BM - 1) / BM, 256, 0, stream>>>(nodes, weight, Hm);
    k_att<<<(NN * HEADS + 255) / 256, 256, 0, stream>>>(Hm, att, ai, aj);
    k_gather<<<(NN * 64 + 255) / 256, 256, 0, stream>>>(rowp, esrc, ai, aj, Hm, bias, out);
}

// Round 10
// 296.680 us; speedup vs baseline: 3.0038x; 1.0665x over previous
//
#include <hip/hip_runtime.h>
#include <hip/hip_bf16.h>
#include <math.h>

#define NN 50000
#define NE 800000
#define IN_CH 256
#define HEADS 4
#define OUT_CH 32
#define HC 128            // HEADS*OUT_CH
#define NEG_SLOPE 0.2f
#define GAT_EPS 1e-16f

// parallel scan geometry
#define SBS 1024
#define NB  ((NN + SBS - 1) / SBS)   // 49

// workspace layout, in 4-byte units
#define OFF_HB     0                        // NN*HC bf16 = NN*HC/2 float units
#define OFF_WT     (NN*HC/2)                // 128*256 bf16 = 16384 float units
#define OFF_AI     (OFF_WT + 16384)         // NN*HEADS floats
#define OFF_AJ     (OFF_AI + NN*HEADS)
#define OFF_ROW    (OFF_AJ + NN*HEADS)      // NN+1 ints
#define OFF_CUR    (OFF_ROW + NN + 4)
#define OFF_HIST   (OFF_CUR + NN + 4)
#define OFF_BSUM   (OFF_HIST + NN + 4)
#define OFF_BOFF   (OFF_BSUM + NB + 4)
#define OFF_ESRC   (OFF_BOFF + NB + 4)      // NE ints

typedef __attribute__((ext_vector_type(8))) short short8v;   // 8 bf16
typedef __attribute__((ext_vector_type(4))) float float4v;

__device__ __forceinline__ unsigned short f2bf(float x) {
    union { float f; unsigned u; } v; v.f = x;
    unsigned r = v.u + 0x7fffu + ((v.u >> 16) & 1u);   // RNE
    return (unsigned short)(r >> 16);
}
__device__ __forceinline__ float bf2f(unsigned short b) {
    union { unsigned u; float f; } v; v.u = ((unsigned)b) << 16;
    return v.f;
}

__global__ void k_zero(int* __restrict__ hist) {
    int i = blockIdx.x * blockDim.x + threadIdx.x;
    if (i < NN) hist[i] = 0;
}

// W[256][128] fp32 -> Wt[128][256] bf16 (transposed)
__global__ void k_wt(const float* __restrict__ W, unsigned short* __restrict__ Wt) {
    int idx = blockIdx.x * blockDim.x + threadIdx.x;
    if (idx >= HC * IN_CH) return;
    int n = idx >> 8, k = idx & 255;
    Wt[n * IN_CH + k] = f2bf(W[(size_t)k * HC + n]);
}

// MFMA bf16 GEMM: Hb[n][c] = bf16( sum_k A[n][k]*W[k][c] )
// block: 256 thr = 4 waves (2x2), tile 128 rows x 128 cols, full K=256
__global__ __launch_bounds__(256) void k_gemm(const float* __restrict__ A,
                                              const unsigned short* __restrict__ Wt,
                                              unsigned short* __restrict__ Hb) {
    const int tid  = threadIdx.x;
    const int lane = tid & 63;
    const int w    = tid >> 6;
    const int wr   = w >> 1, wc = w & 1;
    const int blockRow = blockIdx.x * 128;

    const int lrow = lane & 15;          // row/col within 16
    const int kgrp = lane >> 4;          // 0..3 -> k-subgroup of 8

    float4v acc[4][4];
#pragma unroll
    for (int i = 0; i < 4; i++)
#pragma unroll
        for (int j = 0; j < 4; j++) acc[i][j] = (float4v){0.f, 0.f, 0.f, 0.f};

#pragma unroll
    for (int ks = 0; ks < 8; ks++) {     // K steps of 32
        const int kb = ks * 32 + kgrp * 8;
        short8v af[4], bfr[4];
#pragma unroll
        for (int mi = 0; mi < 4; mi++) {
            int r = blockRow + wr * 64 + mi * 16 + lrow;
            if (r >= NN) r = NN - 1;                    // clamp; stores guarded
            const float* ap = A + (size_t)r * IN_CH + kb;
            float4 a0 = *(const float4*)ap;
            float4 a1 = *(const float4*)(ap + 4);
            short8v t;
            t[0] = (short)f2bf(a0.x); t[1] = (short)f2bf(a0.y);
            t[2] = (short)f2bf(a0.z); t[3] = (short)f2bf(a0.w);
            t[4] = (short)f2bf(a1.x); t[5] = (short)f2bf(a1.y);
            t[6] = (short)f2bf(a1.z); t[7] = (short)f2bf(a1.w);
            af[mi] = t;
        }
#pragma unroll
        for (int ni = 0; ni < 4; ni++) {
            int c = wc * 64 + ni * 16 + lrow;
            bfr[ni] = *(const short8v*)(Wt + (size_t)c * IN_CH + kb);
        }
#pragma unroll
        for (int mi = 0; mi < 4; mi++)
#pragma unroll
            for (int ni = 0; ni < 4; ni++)
                acc[mi][ni] = __builtin_amdgcn_mfma_f32_16x16x32_bf16(
                    af[mi], bfr[ni], acc[mi][ni], 0, 0, 0);
    }

    // D layout: row = (lane>>4)*4 + reg, col = lane&15
#pragma unroll
    for (int mi = 0; mi < 4; mi++) {
#pragma unroll
        for (int reg = 0; reg < 4; reg++) {
            int r = blockRow + wr * 64 + mi * 16 + kgrp * 4 + reg;
            if (r >= NN) continue;
#pragma unroll
            for (int ni = 0; ni < 4; ni++) {
                int c = wc * 64 + ni * 16 + lrow;
                Hb[(size_t)r * HC + c] = f2bf(acc[mi][ni][reg]);
            }
        }
    }
}

// per-(node,head) attention dots from bf16 h
__global__ void k_att(const unsigned short* __restrict__ Hb, const float* __restrict__ att,
                      float* __restrict__ ai, float* __restrict__ aj) {
    int idx = blockIdx.x * blockDim.x + threadIdx.x;
    if (idx >= NN * HEADS) return;
    int n = idx >> 2, hh = idx & 3;
    const unsigned* hp = (const unsigned*)(Hb + (size_t)n * HC + hh * OUT_CH);
    const float* ati = att + hh * 2 * OUT_CH;
    const float* atj = ati + OUT_CH;
    float si = 0.f, sj = 0.f;
#pragma unroll
    for (int i = 0; i < 16; i++) {
        unsigned u = hp[i];
        float lo = bf2f((unsigned short)(u & 0xffff));
        float hi = bf2f((unsigned short)(u >> 16));
        si = fmaf(lo, ati[2 * i], si);     si = fmaf(hi, ati[2 * i + 1], si);
        sj = fmaf(lo, atj[2 * i], sj);     sj = fmaf(hi, atj[2 * i + 1], sj);
    }
    ai[idx] = si;
    aj[idx] = sj;
}

__global__ void k_hist(const int* __restrict__ adj, int* __restrict__ hist) {
    int e = blockIdx.x * blockDim.x + threadIdx.x;
    if (e < NE) atomicAdd(&hist[adj[e]], 1);
}

// scan A: per-block (1024 elems) sum -> bsum[NB]
__global__ __launch_bounds__(256) void k_bsum(const int* __restrict__ hist,
                                              int* __restrict__ bsum) {
    int b = blockIdx.x, t = threadIdx.x;
    int i0 = b * SBS + t * 4;
    int s = 0;
#pragma unroll
    for (int j = 0; j < 4; j++) {
        int i = i0 + j;
        if (i < NN) s += hist[i];
    }
#pragma unroll
    for (int off = 32; off; off >>= 1) s += __shfl_xor(s, off);
    __shared__ int ws[4];
    int lane = t & 63, wid = t >> 6;
    if (lane == 0) ws[wid] = s;
    __syncthreads();
    if (t == 0) bsum[b] = ws[0] + ws[1] + ws[2] + ws[3];
}

// scan B: one wave exclusive-scans bsum
__global__ __launch_bounds__(64) void k_bscan(const int* __restrict__ bsum,
                                              int* __restrict__ boff) {
    int lane = threadIdx.x;
    int v = (lane < NB) ? bsum[lane] : 0;
    int inc = v;
#pragma unroll
    for (int off = 1; off < 64; off <<= 1) {
        int u = __shfl_up(inc, off);
        if (lane >= off) inc += u;
    }
    if (lane < NB) boff[lane] = inc - v;
}

// scan C: block-local exclusive scan + block offset
__global__ __launch_bounds__(256) void k_bwrite(const int* __restrict__ hist,
                                                const int* __restrict__ boff,
                                                int* __restrict__ row,
                                                int* __restrict__ cur) {
    int b = blockIdx.x, t = threadIdx.x;
    int i0 = b * SBS + t * 4;
    int v[4];
    int s = 0;
#pragma unroll
    for (int j = 0; j < 4; j++) {
        int i = i0 + j;
        v[j] = (i < NN) ? hist[i] : 0;
        s += v[j];
    }
    int lane = t & 63, wid = t >> 6;
    int inc = s;
#pragma unroll
    for (int off = 1; off < 64; off <<= 1) {
        int u = __shfl_up(inc, off);
        if (lane >= off) inc += u;
    }
    __shared__ int wsum[4];
    if (lane == 63) wsum[wid] = inc;
    __syncthreads();
    int woff = 0;
    for (int w2 = 0; w2 < wid; w2++) woff += wsum[w2];
    int run = boff[b] + woff + (inc - s);
#pragma unroll
    for (int j = 0; j < 4; j++) {
        int i = i0 + j;
        if (i < NN) {
            row[i] = run;
            cur[i] = run;
            run += v[j];
        }
    }
    if (b == 0 && t == 0) row[NN] = NE;
}

__global__ void k_scatter(const int* __restrict__ adj, int* __restrict__ cur,
                          int* __restrict__ esrc) {
    int e = blockIdx.x * blockDim.x + threadIdx.x;
    if (e >= NE) return;
    int dst = adj[e];
    int src = adj[NE + e];
    int pos = atomicAdd(&cur[dst], 1);
    esrc[pos] = src;
}

__device__ __forceinline__ float lrelu(float x) {
    return x > 0.f ? x : NEG_SLOPE * x;
}

// one wave per node: segment-max, exp-sum, weighted gather (bf16 h rows)
__global__ __launch_bounds__(256) void k_gather(const int* __restrict__ row,
                                                const int* __restrict__ esrc,
                                                const float* __restrict__ ai,
                                                const float* __restrict__ aj,
                                                const unsigned short* __restrict__ Hb,
                                                const float* __restrict__ bias,
                                                float* __restrict__ out) {
    int gid = blockIdx.x * blockDim.x + threadIdx.x;
    int nid = gid >> 6;
    int lane = gid & 63;
    if (nid >= NN) return;
    int r0 = row[nid];
    int deg = row[nid + 1] - r0;

    float4 aiv = *(const float4*)&ai[nid * 4];

    // pass 1: per-head max
    float mx0 = -INFINITY, mx1 = -INFINITY, mx2 = -INFINITY, mx3 = -INFINITY;
    for (int k = lane; k < deg; k += 64) {
        int s = esrc[r0 + k];
        float4 ajv = *(const float4*)&aj[s * 4];
        mx0 = fmaxf(mx0, lrelu(aiv.x + ajv.x));
        mx1 = fmaxf(mx1, lrelu(aiv.y + ajv.y));
        mx2 = fmaxf(mx2, lrelu(aiv.z + ajv.z));
        mx3 = fmaxf(mx3, lrelu(aiv.w + ajv.w));
    }
#pragma unroll
    for (int off = 32; off; off >>= 1) {
        mx0 = fmaxf(mx0, __shfl_xor(mx0, off));
        mx1 = fmaxf(mx1, __shfl_xor(mx1, off));
        mx2 = fmaxf(mx2, __shfl_xor(mx2, off));
        mx3 = fmaxf(mx3, __shfl_xor(mx3, off));
    }

    // pass 2: per-head exp-sum
    float s0 = 0.f, s1 = 0.f, s2 = 0.f, s3 = 0.f;
    for (int k = lane; k < deg; k += 64) {
        int s = esrc[r0 + k];
        float4 ajv = *(const float4*)&aj[s * 4];
        s0 += __expf(lrelu(aiv.x + ajv.x) - mx0);
        s1 += __expf(lrelu(aiv.y + ajv.y) - mx1);
        s2 += __expf(lrelu(aiv.z + ajv.z) - mx2);
        s3 += __expf(lrelu(aiv.w + ajv.w) - mx3);
    }
#pragma unroll
    for (int off = 32; off; off >>= 1) {
        s0 += __shfl_xor(s0, off);
        s1 += __shfl_xor(s1, off);
        s2 += __shfl_xor(s2, off);
        s3 += __shfl_xor(s3, off);
    }

    // pass 3: weighted aggregation; lane owns channels c0, c0+1 (head hh)
    int c0 = lane * 2;
    int hh = lane >> 4;
    float mh  = (hh & 2) ? ((hh & 1) ? mx3 : mx2) : ((hh & 1) ? mx1 : mx0);
    float sh  = (hh & 2) ? ((hh & 1) ? s3 : s2) : ((hh & 1) ? s1 : s0);
    float aih = (hh & 2) ? ((hh & 1) ? aiv.w : aiv.z) : ((hh & 1) ? aiv.y : aiv.x);
    float inv = 1.0f / (sh + GAT_EPS);

    float accx = 0.f, accy = 0.f;
#pragma unroll 4
    for (int k = 0; k < deg; k++) {
        int s = esrc[r0 + k];           // uniform across wave -> broadcast
        float al = lrelu(aih + aj[s * 4 + hh]);
        float a = __expf(al - mh) * inv;
        unsigned hu = *(const unsigned*)(Hb + (size_t)s * HC + c0);
        accx = fmaf(bf2f((unsigned short)(hu & 0xffff)), a, accx);
        accy = fmaf(bf2f((unsigned short)(hu >> 16)), a, accy);
    }
    out[(size_t)nid * HC + c0]     = accx + bias[c0];
    out[(size_t)nid * HC + c0 + 1] = accy + bias[c0 + 1];
}

extern "C" void kernel_launch(void* const* d_in, const int* in_sizes, int n_in,
                              void* d_out, int out_size, void* d_ws, size_t ws_size,
                              hipStream_t stream) {
    const float* nodes  = (const float*)d_in[0];
    const int*   adj    = (const int*)d_in[1];
    const float* weight = (const float*)d_in[2];
    const float* att    = (const float*)d_in[3];
    const float* bias   = (const float*)d_in[4];
    float* out = (float*)d_out;
    float* ws  = (float*)d_ws;

    unsigned short* Hb = (unsigned short*)(ws + OFF_HB);
    unsigned short* Wt = (unsigned short*)(ws + OFF_WT);
    float* ai   = ws + OFF_AI;
    float* aj   = ws + OFF_AJ;
    int*   rowp = (int*)(ws + OFF_ROW);
    int*   cur  = (int*)(ws + OFF_CUR);
    int*   hist = (int*)(ws + OFF_HIST);
    int*   bsum = (int*)(ws + OFF_BSUM);
    int*   boff = (int*)(ws + OFF_BOFF);
    int*   esrc = (int*)(ws + OFF_ESRC);

    k_zero<<<(NN + 255) / 256, 256, 0, stream>>>(hist);
    k_hist<<<(NE + 255) / 256, 256, 0, stream>>>(adj, hist);
    k_bsum<<<NB, 256, 0, stream>>>(hist, bsum);
    k_bscan<<<1, 64, 0, stream>>>(bsum, boff);
    k_bwrite<<<NB, 256, 0, stream>>>(hist, boff, rowp, cur);
    k_scatter<<<(NE + 255) / 256, 256, 0, stream>>>(adj, cur, esrc);
    k_wt<<<(HC * IN_CH + 255) / 256, 256, 0, stream>>>(weight, Wt);
    k_gemm<<<(NN + 127) / 128, 256, 0, stream>>>(nodes, Wt, Hb);
    k_att<<<(NN * HEADS + 255) / 256, 256, 0, stream>>>(Hb, att, ai, aj);
    k_gather<<<(NN * 64 + 255) / 256, 256, 0, stream>>>(rowp, esrc, ai, aj, Hb, bias, out);
}

// Round 11
// 275.219 us; speedup vs baseline: 3.2381x; 1.0780x over previous
//
#include <hip/hip_runtime.h>
#include <hip/hip_bf16.h>
#include <math.h>

#define NN 50000
#define NE 800000
#define IN_CH 256
#define HEADS 4
#define OUT_CH 32
#define HC 128            // HEADS*OUT_CH
#define NEG_SLOPE 0.2f
#define GAT_EPS 1e-16f

// parallel scan geometry (node hist scan)
#define SBS 1024
#define NB  ((NN + SBS - 1) / SBS)   // 49

// binned scatter geometry
#define NBINS 64          // allocated bins (49 used)
#define BINSH 10          // bin = dst >> 10 (1024 nodes/bin)
#define NBBIN 49          // ceil(NN/1024)
#define NBLK  625         // edge blocks
#define EPB   1280        // 625*1280 = 800000 exactly (5 iters x 256 thr)

// workspace layout, in 4-byte units
#define OFF_HB     0                          // NN*HC bf16
#define OFF_WT     (NN*HC/2)                  // 128*256 bf16
#define OFF_AI     (OFF_WT + 16384)
#define OFF_AJ     (OFF_AI + NN*HEADS)
#define OFF_ROW    (OFF_AJ + NN*HEADS)        // NN+1 ints
#define OFF_CUR    (OFF_ROW + NN + 4)
#define OFF_HIST   (OFF_CUR + NN + 4)
#define OFF_BSUM   (OFF_HIST + NN + 4)
#define OFF_BOFF   (OFF_BSUM + NB + 4)
#define OFF_BLKC   (OFF_BOFF + NB + 4)        // NBLK*NBINS ints
#define OFF_BLKO   (OFF_BLKC + NBLK*NBINS)    // NBLK*NBINS ints
#define OFF_PAIR   ((OFF_BLKO + NBLK*NBINS + 1) & ~1)  // NE int2 (8B aligned)
#define OFF_ESRC   (OFF_PAIR + 2*NE)          // NE ints

typedef __attribute__((ext_vector_type(8))) short short8v;   // 8 bf16
typedef __attribute__((ext_vector_type(4))) float float4v;

__device__ __forceinline__ unsigned short f2bf(float x) {
    union { float f; unsigned u; } v; v.f = x;
    unsigned r = v.u + 0x7fffu + ((v.u >> 16) & 1u);   // RNE
    return (unsigned short)(r >> 16);
}
__device__ __forceinline__ float bf2f(unsigned short b) {
    union { unsigned u; float f; } v; v.u = ((unsigned)b) << 16;
    return v.f;
}

__global__ void k_zero(int* __restrict__ hist) {
    int i = blockIdx.x * blockDim.x + threadIdx.x;
    if (i < NN) hist[i] = 0;
}

// W[256][128] fp32 -> Wt[128][256] bf16 (transposed)
__global__ void k_wt(const float* __restrict__ W, unsigned short* __restrict__ Wt) {
    int idx = blockIdx.x * blockDim.x + threadIdx.x;
    if (idx >= HC * IN_CH) return;
    int n = idx >> 8, k = idx & 255;
    Wt[n * IN_CH + k] = f2bf(W[(size_t)k * HC + n]);
}

// MFMA bf16 GEMM: Hb[n][c] = bf16( sum_k A[n][k]*W[k][c] )
__global__ __launch_bounds__(256) void k_gemm(const float* __restrict__ A,
                                              const unsigned short* __restrict__ Wt,
                                              unsigned short* __restrict__ Hb) {
    const int tid  = threadIdx.x;
    const int lane = tid & 63;
    const int w    = tid >> 6;
    const int wr   = w >> 1, wc = w & 1;
    const int blockRow = blockIdx.x * 128;

    const int lrow = lane & 15;
    const int kgrp = lane >> 4;

    float4v acc[4][4];
#pragma unroll
    for (int i = 0; i < 4; i++)
#pragma unroll
        for (int j = 0; j < 4; j++) acc[i][j] = (float4v){0.f, 0.f, 0.f, 0.f};

#pragma unroll
    for (int ks = 0; ks < 8; ks++) {
        const int kb = ks * 32 + kgrp * 8;
        short8v af[4], bfr[4];
#pragma unroll
        for (int mi = 0; mi < 4; mi++) {
            int r = blockRow + wr * 64 + mi * 16 + lrow;
            if (r >= NN) r = NN - 1;
            const float* ap = A + (size_t)r * IN_CH + kb;
            float4 a0 = *(const float4*)ap;
            float4 a1 = *(const float4*)(ap + 4);
            short8v t;
            t[0] = (short)f2bf(a0.x); t[1] = (short)f2bf(a0.y);
            t[2] = (short)f2bf(a0.z); t[3] = (short)f2bf(a0.w);
            t[4] = (short)f2bf(a1.x); t[5] = (short)f2bf(a1.y);
            t[6] = (short)f2bf(a1.z); t[7] = (short)f2bf(a1.w);
            af[mi] = t;
        }
#pragma unroll
        for (int ni = 0; ni < 4; ni++) {
            int c = wc * 64 + ni * 16 + lrow;
            bfr[ni] = *(const short8v*)(Wt + (size_t)c * IN_CH + kb);
        }
#pragma unroll
        for (int mi = 0; mi < 4; mi++)
#pragma unroll
            for (int ni = 0; ni < 4; ni++)
                acc[mi][ni] = __builtin_amdgcn_mfma_f32_16x16x32_bf16(
                    af[mi], bfr[ni], acc[mi][ni], 0, 0, 0);
    }

#pragma unroll
    for (int mi = 0; mi < 4; mi++) {
#pragma unroll
        for (int reg = 0; reg < 4; reg++) {
            int r = blockRow + wr * 64 + mi * 16 + kgrp * 4 + reg;
            if (r >= NN) continue;
#pragma unroll
            for (int ni = 0; ni < 4; ni++) {
                int c = wc * 64 + ni * 16 + lrow;
                Hb[(size_t)r * HC + c] = f2bf(acc[mi][ni][reg]);
            }
        }
    }
}

// per-(node,head) attention dots from bf16 h
__global__ void k_att(const unsigned short* __restrict__ Hb, const float* __restrict__ att,
                      float* __restrict__ ai, float* __restrict__ aj) {
    int idx = blockIdx.x * blockDim.x + threadIdx.x;
    if (idx >= NN * HEADS) return;
    int n = idx >> 2, hh = idx & 3;
    const unsigned* hp = (const unsigned*)(Hb + (size_t)n * HC + hh * OUT_CH);
    const float* ati = att + hh * 2 * OUT_CH;
    const float* atj = ati + OUT_CH;
    float si = 0.f, sj = 0.f;
#pragma unroll
    for (int i = 0; i < 16; i++) {
        unsigned u = hp[i];
        float lo = bf2f((unsigned short)(u & 0xffff));
        float hi = bf2f((unsigned short)(u >> 16));
        si = fmaf(lo, ati[2 * i], si);     si = fmaf(hi, ati[2 * i + 1], si);
        sj = fmaf(lo, atj[2 * i], sj);     sj = fmaf(hi, atj[2 * i + 1], sj);
    }
    ai[idx] = si;
    aj[idx] = sj;
}

// binned scatter phase 1: node histogram + per-block bin counts
__global__ __launch_bounds__(256) void s_count(const int* __restrict__ adj,
                                               int* __restrict__ hist,
                                               int* __restrict__ blkcnt) {
    __shared__ int lh[NBINS];
    int b = blockIdx.x, t = threadIdx.x;
    if (t < NBINS) lh[t] = 0;
    __syncthreads();
    int e0 = b * EPB;
#pragma unroll
    for (int i = 0; i < 5; i++) {
        int e = e0 + i * 256 + t;               // exact: 625*1280 == NE
        int dst = adj[e];
        atomicAdd(&hist[dst], 1);
        atomicAdd(&lh[dst >> BINSH], 1);
    }
    __syncthreads();
    if (t < NBINS) blkcnt[b * NBINS + t] = lh[t];
}

// binned scatter phase 2: per-bin exclusive scan over the 625 block counts
__global__ __launch_bounds__(640) void s_scanblk(const int* __restrict__ blkcnt,
                                                 int* __restrict__ blkoff) {
    int bin = blockIdx.x, t = threadIdx.x;
    int c = (t < NBLK) ? blkcnt[t * NBINS + bin] : 0;
    int lane = t & 63, w = t >> 6;
    int inc = c;
#pragma unroll
    for (int off = 1; off < 64; off <<= 1) {
        int u = __shfl_up(inc, off);
        if (lane >= off) inc += u;
    }
    __shared__ int wsum[10];
    if (lane == 63) wsum[w] = inc;
    __syncthreads();
    int wpre = 0;
    for (int i = 0; i < w; i++) wpre += wsum[i];
    if (t < NBLK) blkoff[t * NBINS + bin] = wpre + inc - c;   // exclusive
}

// binned scatter phase 3: write (dst,src) pairs, bin-grouped, coalesced runs
__global__ __launch_bounds__(256) void s_pairs(const int* __restrict__ adj,
                                               const int* __restrict__ rowp,
                                               const int* __restrict__ blkoff,
                                               int2* __restrict__ paired) {
    __shared__ int lh[NBINS];
    __shared__ int base[NBINS];
    int b = blockIdx.x, t = threadIdx.x;
    if (t < NBINS) {
        lh[t] = 0;
        int n0 = t << BINSH;
        base[t] = rowp[n0 < NN ? n0 : NN] + blkoff[b * NBINS + t];
    }
    __syncthreads();
    int e0 = b * EPB;
#pragma unroll
    for (int i = 0; i < 5; i++) {
        int e = e0 + i * 256 + t;
        int dst = adj[e];
        int src = adj[NE + e];
        int bin = dst >> BINSH;
        int r = atomicAdd(&lh[bin], 1);
        paired[base[bin] + r] = make_int2(dst, src);
    }
}

// binned scatter phase 4: exact CSR within each bin's contiguous window
__global__ __launch_bounds__(256) void s_csr(const int2* __restrict__ paired,
                                             const int* __restrict__ rowp,
                                             int* __restrict__ esrc) {
    __shared__ int cur2[1 << BINSH];
    int b = blockIdx.x, t = threadIdx.x;
    for (int i = t; i < (1 << BINSH); i += 256) cur2[i] = 0;
    __syncthreads();
    int n0 = b << BINSH;
    int n1 = n0 + (1 << BINSH); if (n1 > NN) n1 = NN;
    int e0 = rowp[n0], e1 = rowp[n1];
    for (int i = e0 + t; i < e1; i += 256) {
        int2 p = paired[i];
        int off = atomicAdd(&cur2[p.x - n0], 1);
        esrc[rowp[p.x] + off] = p.y;
    }
}

// scan A: per-block (1024 elems) sum -> bsum[NB]
__global__ __launch_bounds__(256) void k_bsum(const int* __restrict__ hist,
                                              int* __restrict__ bsum) {
    int b = blockIdx.x, t = threadIdx.x;
    int i0 = b * SBS + t * 4;
    int s = 0;
#pragma unroll
    for (int j = 0; j < 4; j++) {
        int i = i0 + j;
        if (i < NN) s += hist[i];
    }
#pragma unroll
    for (int off = 32; off; off >>= 1) s += __shfl_xor(s, off);
    __shared__ int ws[4];
    int lane = t & 63, wid = t >> 6;
    if (lane == 0) ws[wid] = s;
    __syncthreads();
    if (t == 0) bsum[b] = ws[0] + ws[1] + ws[2] + ws[3];
}

// scan B: one wave exclusive-scans bsum
__global__ __launch_bounds__(64) void k_bscan(const int* __restrict__ bsum,
                                              int* __restrict__ boff) {
    int lane = threadIdx.x;
    int v = (lane < NB) ? bsum[lane] : 0;
    int inc = v;
#pragma unroll
    for (int off = 1; off < 64; off <<= 1) {
        int u = __shfl_up(inc, off);
        if (lane >= off) inc += u;
    }
    if (lane < NB) boff[lane] = inc - v;
}

// scan C: block-local exclusive scan + block offset -> row; row[NN]=NE
__global__ __launch_bounds__(256) void k_bwrite(const int* __restrict__ hist,
                                                const int* __restrict__ boff,
                                                int* __restrict__ row,
                                                int* __restrict__ cur) {
    int b = blockIdx.x, t = threadIdx.x;
    int i0 = b * SBS + t * 4;
    int v[4];
    int s = 0;
#pragma unroll
    for (int j = 0; j < 4; j++) {
        int i = i0 + j;
        v[j] = (i < NN) ? hist[i] : 0;
        s += v[j];
    }
    int lane = t & 63, wid = t >> 6;
    int inc = s;
#pragma unroll
    for (int off = 1; off < 64; off <<= 1) {
        int u = __shfl_up(inc, off);
        if (lane >= off) inc += u;
    }
    __shared__ int wsum[4];
    if (lane == 63) wsum[wid] = inc;
    __syncthreads();
    int woff = 0;
    for (int w2 = 0; w2 < wid; w2++) woff += wsum[w2];
    int run = boff[b] + woff + (inc - s);
#pragma unroll
    for (int j = 0; j < 4; j++) {
        int i = i0 + j;
        if (i < NN) {
            row[i] = run;
            cur[i] = run;
            run += v[j];
        }
    }
    if (b == 0 && t == 0) row[NN] = NE;
}

__device__ __forceinline__ float lrelu(float x) {
    return x > 0.f ? x : NEG_SLOPE * x;
}

// one wave per node: segment-max, exp-sum, weighted gather (bf16 h rows)
__global__ __launch_bounds__(256) void k_gather(const int* __restrict__ row,
                                                const int* __restrict__ esrc,
                                                const float* __restrict__ ai,
                                                const float* __restrict__ aj,
                                                const unsigned short* __restrict__ Hb,
                                                const float* __restrict__ bias,
                                                float* __restrict__ out) {
    int gid = blockIdx.x * blockDim.x + threadIdx.x;
    int nid = gid >> 6;
    int lane = gid & 63;
    if (nid >= NN) return;
    int r0 = row[nid];
    int deg = row[nid + 1] - r0;

    float4 aiv = *(const float4*)&ai[nid * 4];

    // pass 1: per-head max
    float mx0 = -INFINITY, mx1 = -INFINITY, mx2 = -INFINITY, mx3 = -INFINITY;
    for (int k = lane; k < deg; k += 64) {
        int s = esrc[r0 + k];
        float4 ajv = *(const float4*)&aj[s * 4];
        mx0 = fmaxf(mx0, lrelu(aiv.x + ajv.x));
        mx1 = fmaxf(mx1, lrelu(aiv.y + ajv.y));
        mx2 = fmaxf(mx2, lrelu(aiv.z + ajv.z));
        mx3 = fmaxf(mx3, lrelu(aiv.w + ajv.w));
    }
#pragma unroll
    for (int off = 32; off; off >>= 1) {
        mx0 = fmaxf(mx0, __shfl_xor(mx0, off));
        mx1 = fmaxf(mx1, __shfl_xor(mx1, off));
        mx2 = fmaxf(mx2, __shfl_xor(mx2, off));
        mx3 = fmaxf(mx3, __shfl_xor(mx3, off));
    }

    // pass 2: per-head exp-sum
    float s0 = 0.f, s1 = 0.f, s2 = 0.f, s3 = 0.f;
    for (int k = lane; k < deg; k += 64) {
        int s = esrc[r0 + k];
        float4 ajv = *(const float4*)&aj[s * 4];
        s0 += __expf(lrelu(aiv.x + ajv.x) - mx0);
        s1 += __expf(lrelu(aiv.y + ajv.y) - mx1);
        s2 += __expf(lrelu(aiv.z + ajv.z) - mx2);
        s3 += __expf(lrelu(aiv.w + ajv.w) - mx3);
    }
#pragma unroll
    for (int off = 32; off; off >>= 1) {
        s0 += __shfl_xor(s0, off);
        s1 += __shfl_xor(s1, off);
        s2 += __shfl_xor(s2, off);
        s3 += __shfl_xor(s3, off);
    }

    // pass 3: weighted aggregation; lane owns channels c0, c0+1 (head hh)
    int c0 = lane * 2;
    int hh = lane >> 4;
    float mh  = (hh & 2) ? ((hh & 1) ? mx3 : mx2) : ((hh & 1) ? mx1 : mx0);
    float sh  = (hh & 2) ? ((hh & 1) ? s3 : s2) : ((hh & 1) ? s1 : s0);
    float aih = (hh & 2) ? ((hh & 1) ? aiv.w : aiv.z) : ((hh & 1) ? aiv.y : aiv.x);
    float inv = 1.0f / (sh + GAT_EPS);

    float accx = 0.f, accy = 0.f;
#pragma unroll 4
    for (int k = 0; k < deg; k++) {
        int s = esrc[r0 + k];           // uniform across wave -> broadcast
        float al = lrelu(aih + aj[s * 4 + hh]);
        float a = __expf(al - mh) * inv;
        unsigned hu = *(const unsigned*)(Hb + (size_t)s * HC + c0);
        accx = fmaf(bf2f((unsigned short)(hu & 0xffff)), a, accx);
        accy = fmaf(bf2f((unsigned short)(hu >> 16)), a, accy);
    }
    out[(size_t)nid * HC + c0]     = accx + bias[c0];
    out[(size_t)nid * HC + c0 + 1] = accy + bias[c0 + 1];
}

extern "C" void kernel_launch(void* const* d_in, const int* in_sizes, int n_in,
                              void* d_out, int out_size, void* d_ws, size_t ws_size,
                              hipStream_t stream) {
    const float* nodes  = (const float*)d_in[0];
    const int*   adj    = (const int*)d_in[1];
    const float* weight = (const float*)d_in[2];
    const float* att    = (const float*)d_in[3];
    const float* bias   = (const float*)d_in[4];
    float* out = (float*)d_out;
    float* ws  = (float*)d_ws;

    unsigned short* Hb = (unsigned short*)(ws + OFF_HB);
    unsigned short* Wt = (unsigned short*)(ws + OFF_WT);
    float* ai    = ws + OFF_AI;
    float* aj    = ws + OFF_AJ;
    int*   rowp  = (int*)(ws + OFF_ROW);
    int*   cur   = (int*)(ws + OFF_CUR);
    int*   hist  = (int*)(ws + OFF_HIST);
    int*   bsum  = (int*)(ws + OFF_BSUM);
    int*   boff  = (int*)(ws + OFF_BOFF);
    int*   blkc  = (int*)(ws + OFF_BLKC);
    int*   blko  = (int*)(ws + OFF_BLKO);
    int2*  pair  = (int2*)(ws + OFF_PAIR);
    int*   esrc  = (int*)(ws + OFF_ESRC);

    k_zero<<<(NN + 255) / 256, 256, 0, stream>>>(hist);
    s_count<<<NBLK, 256, 0, stream>>>(adj, hist, blkc);
    k_bsum<<<NB, 256, 0, stream>>>(hist, bsum);
    k_bscan<<<1, 64, 0, stream>>>(bsum, boff);
    k_bwrite<<<NB, 256, 0, stream>>>(hist, boff, rowp, cur);
    s_scanblk<<<NBINS, 640, 0, stream>>>(blkc, blko);
    s_pairs<<<NBLK, 256, 0, stream>>>(adj, rowp, blko, pair);
    s_csr<<<NBBIN, 256, 0, stream>>>(pair, rowp, esrc);
    k_wt<<<(HC * IN_CH + 255) / 256, 256, 0, stream>>>(weight, Wt);
    k_gemm<<<(NN + 127) / 128, 256, 0, stream>>>(nodes, Wt, Hb);
    k_att<<<(NN * HEADS + 255) / 256, 256, 0, stream>>>(Hb, att, ai, aj);
    k_gather<<<(NN * 64 + 255) / 256, 256, 0, stream>>>(rowp, esrc, ai, aj, Hb, bias, out);
}